// Round 1
// baseline (491.582 us; speedup 1.0000x reference)
//
#include <hip/hip_runtime.h>

typedef unsigned short u16;
typedef unsigned int   u32;
typedef float f32x4 __attribute__((ext_vector_type(4)));
typedef u32   u32x4 __attribute__((ext_vector_type(4)));
typedef __bf16 bf16x8 __attribute__((ext_vector_type(8)));

// ---------------- workspace byte offsets (total 0x3180000 = 51.9 MB) ----------
#define OFF_X    0x0000000ULL  // x bf16            (8192*256)   4 MB
#define OFF_WQ   0x0400000ULL  // Wq bf16           (256*256)
#define OFF_WK   0x0420000ULL
#define OFF_WV   0x0440000ULL
#define OFF_WO   0x0460000ULL
#define OFF_W1   0x0480000ULL  // (1024*256)
#define OFF_W2   0x0500000ULL  // (256*1024)
#define OFF_Q    0x0580000ULL  // Q  bf16 (B,H,T,D) 4 MB
#define OFF_K    0x0980000ULL  // K  bf16 (B,H,T,D) 4 MB
#define OFF_VT   0x0D80000ULL  // V^T bf16 (B,H,D,T) row-permuted within 32-tiles, 4 MB
#define OFF_CTX  0x1180000ULL  // ctx bf16 (8192,256) 4 MB
#define OFF_X1F  0x1580000ULL  // x1 f32  (8192,256) 8 MB
#define OFF_X1B  0x1D80000ULL  // x1 bf16            4 MB
#define OFF_H    0x2180000ULL  // h bf16 (8192,1024) 16 MB

__device__ __forceinline__ u16 f2bf(float f){
  u32 u = __float_as_uint(f);
  return (u16)((u + 0x7FFFu + ((u >> 16) & 1u)) >> 16);
}
__device__ __forceinline__ bf16x8 ld_bf8(const u16* p){
  return *(const bf16x8*)p;   // 16B global load; p always 16B aligned
}
__device__ __forceinline__ f32x4 MFMA(bf16x8 a, bf16x8 b, f32x4 c){
  return __builtin_amdgcn_mfma_f32_16x16x32_bf16(a, b, c, 0, 0, 0);
}
template<int C>
__device__ __forceinline__ float dpp_rot(float x){
  int i = __float_as_int(x);
  return __int_as_float(__builtin_amdgcn_update_dpp(i, i, C, 0xF, 0xF, false));
}
// all-reduce across the 16 lanes of a DPP row (ror 1,2,4,8)
__device__ __forceinline__ float rmax16(float x){
  x = fmaxf(x, dpp_rot<0x121>(x)); x = fmaxf(x, dpp_rot<0x122>(x));
  x = fmaxf(x, dpp_rot<0x124>(x)); x = fmaxf(x, dpp_rot<0x128>(x));
  return x;
}
__device__ __forceinline__ float rsum16(float x){
  x += dpp_rot<0x121>(x); x += dpp_rot<0x122>(x);
  x += dpp_rot<0x124>(x); x += dpp_rot<0x128>(x);
  return x;
}

// ---------------- kernel 0: convert x + all weights to bf16 -------------------
__global__ __launch_bounds__(256) void prep_kernel(
    const float* __restrict__ x,  const float* __restrict__ Wq,
    const float* __restrict__ Wk, const float* __restrict__ Wv,
    const float* __restrict__ Wo, const float* __restrict__ W1,
    const float* __restrict__ W2, u16* __restrict__ dst)
{
  int i = blockIdx.x * 256 + threadIdx.x;   // grid sized exactly to 2883584
  float v;
  if (i < 2097152) v = x[i];
  else {
    int j = i - 2097152;
    if      (j <  65536) v = Wq[j];
    else if (j < 131072) v = Wk[j -  65536];
    else if (j < 196608) v = Wv[j - 131072];
    else if (j < 262144) v = Wo[j - 196608];
    else if (j < 524288) v = W1[j - 262144];
    else                 v = W2[j - 524288];
  }
  dst[i] = f2bf(v);
}

// ---------------- kernel 1: QKV projection ------------------------------------
// grid (256, 3): x = m-block (32 rows of 8192), y = {Q,K,V}. block 512 (8 waves,
// wave w handles output cols 32w..32w+31 of the 256-wide projection).
__global__ __launch_bounds__(512) void qkv_kernel(
    const u16* __restrict__ X, const u16* __restrict__ W3,
    const float* __restrict__ bq, const float* __restrict__ bk,
    const float* __restrict__ bv,
    u16* __restrict__ Q, u16* __restrict__ K, u16* __restrict__ VT)
{
  const int tid = threadIdx.x;
  const int lane = tid & 63, w = tid >> 6;
  const int g = lane >> 4, c = lane & 15;
  const int m0 = blockIdx.x * 32;
  const int nb = blockIdx.y;
  const u16* Wb = W3 + nb * 65536;
  const float* bias = (nb == 0) ? bq : ((nb == 1) ? bk : bv);
  const int n0 = w * 32;

  f32x4 acc[2][2];
  #pragma unroll
  for (int i = 0; i < 2; ++i)
    #pragma unroll
    for (int j = 0; j < 2; ++j){ f32x4 z = {0.f,0.f,0.f,0.f}; acc[i][j] = z; }

  #pragma unroll
  for (int kt = 0; kt < 8; ++kt){
    bf16x8 a0 = ld_bf8(X  + (size_t)(m0 +      c) * 256 + kt*32 + g*8);
    bf16x8 a1 = ld_bf8(X  + (size_t)(m0 + 16 + c) * 256 + kt*32 + g*8);
    bf16x8 b0 = ld_bf8(Wb + (size_t)(n0 +      c) * 256 + kt*32 + g*8);
    bf16x8 b1 = ld_bf8(Wb + (size_t)(n0 + 16 + c) * 256 + kt*32 + g*8);
    acc[0][0] = MFMA(a0, b0, acc[0][0]);
    acc[0][1] = MFMA(a0, b1, acc[0][1]);
    acc[1][0] = MFMA(a1, b0, acc[1][0]);
    acc[1][1] = MFMA(a1, b1, acc[1][1]);
  }

  #pragma unroll
  for (int qt = 0; qt < 2; ++qt)
  #pragma unroll
  for (int nt = 0; nt < 2; ++nt)
  #pragma unroll
  for (int r = 0; r < 4; ++r){
    int mrow = m0 + qt*16 + g*4 + r;
    int col  = n0 + nt*16 + c;
    float v = acc[qt][nt][r] + bias[col];
    int bi = mrow >> 11, t = mrow & 2047;
    int h  = col >> 5,  d = col & 31;
    u16 hv = f2bf(v);
    if (nb == 0)      Q[((size_t)(bi*8 + h) * 2048 + t) * 32 + d] = hv;
    else if (nb == 1) K[((size_t)(bi*8 + h) * 2048 + t) * 32 + d] = hv;
    else {
      // store V transposed (B,H,D,T) with t permuted inside each 32-tile so that
      // stored slot s holds actual t-offset 16*(s&1) + (s>>1)  (matches P packing)
      int tl = t & 31;
      int sl = ((tl & 15) << 1) | (tl >> 4);
      VT[((size_t)(bi*8 + h) * 32 + d) * 2048 + (t & ~31) + sl] = hv;
    }
  }
}

// ---------------- kernel 2: fused flash attention with pos bias ---------------
// grid (64, 4): x = q-tile (32 rows), y = batch. block 512: wave = head.
__global__ __launch_bounds__(512) void attn_kernel(
    const float* __restrict__ pos, const float* __restrict__ pad,
    const u16* __restrict__ Q, const u16* __restrict__ K,
    const u16* __restrict__ VT, u16* __restrict__ ctx)
{
  __shared__ u32 p_lds[8][32][20];   // per-wave P tile, 16 dwords used, stride 20
  const int tid = threadIdx.x;
  const int lane = tid & 63, w = tid >> 6;
  const int g = lane >> 4, c = lane & 15;
  const int b = blockIdx.y;
  const int q0 = blockIdx.x * 32;

  const u16* Qb  = Q  + ((size_t)(b*8 + w) * 2048 + q0) * 32;
  const u16* Kb  = K  +  (size_t)(b*8 + w) * 2048 * 32;
  const u16* VTb = VT +  (size_t)(b*8 + w) * 32 * 2048;
  const float* posb = pos + (size_t)(b*2048 + q0) * 2048 * 8 + w;
  const float* padb = pad + (size_t)(b*2048 + q0) * 2048;

  bf16x8 qf[2];
  qf[0] = ld_bf8(Qb + (size_t)(     c) * 32 + g*8);
  qf[1] = ld_bf8(Qb + (size_t)(16 + c) * 32 + g*8);

  f32x4 O[2][2];
  #pragma unroll
  for (int i = 0; i < 2; ++i)
    #pragma unroll
    for (int j = 0; j < 2; ++j){ f32x4 z = {0.f,0.f,0.f,0.f}; O[i][j] = z; }
  float m_[2][4], l_[2][4];
  #pragma unroll
  for (int i = 0; i < 2; ++i)
    #pragma unroll
    for (int r = 0; r < 4; ++r){ m_[i][r] = -3.0e38f; l_[i][r] = 0.f; }

  const float c1 = 1.4426950408889634f * 0.17677669529663689f; // log2e / sqrt(32)
  const float c2 = 1.4426950408889634f;                        // log2e

  bf16x8 kf[2], vf[2];
  float pv[2][2][4], pd_[2][2][4];

  auto load_k = [&](int k0){
    kf[0] = ld_bf8(Kb + (size_t)(k0 +      c) * 32 + g*8);
    kf[1] = ld_bf8(Kb + (size_t)(k0 + 16 + c) * 32 + g*8);
  };
  auto load_v = [&](int k0){
    vf[0] = ld_bf8(VTb + (size_t)(     c) * 2048 + k0 + g*8);
    vf[1] = ld_bf8(VTb + (size_t)(16 + c) * 2048 + k0 + g*8);
  };
  auto load_pp = [&](int k0){
    #pragma unroll
    for (int qt = 0; qt < 2; ++qt)
    #pragma unroll
    for (int r = 0; r < 4; ++r){
      int qrel = qt*16 + g*4 + r;
      const float* pq = posb + (size_t)qrel * (2048*8);
      const float* dq = padb + (size_t)qrel * 2048;
      #pragma unroll
      for (int kt = 0; kt < 2; ++kt){
        int k = k0 + kt*16 + c;
        pv[qt][kt][r]  = pq[(size_t)k * 8];
        pd_[qt][kt][r] = dq[k];
      }
    }
  };

  load_k(0); load_v(0); load_pp(0);

  for (int it = 0; it < 64; ++it){
    const int kn = (it < 63) ? (it + 1) * 32 : 0;

    // 1. scores (QK^T), K-dim = D = 32
    f32x4 s[2][2];
    {
      f32x4 z = {0.f,0.f,0.f,0.f};
      s[0][0] = MFMA(qf[0], kf[0], z);
      s[0][1] = MFMA(qf[0], kf[1], z);
      s[1][0] = MFMA(qf[1], kf[0], z);
      s[1][1] = MFMA(qf[1], kf[1], z);
    }
    // 2. logits in base-2: (qk + pos)*log2e/sqrt(D) + pad*log2e
    float sc[2][2][4];
    #pragma unroll
    for (int qt = 0; qt < 2; ++qt)
    #pragma unroll
    for (int kt = 0; kt < 2; ++kt)
    #pragma unroll
    for (int r = 0; r < 4; ++r)
      sc[qt][kt][r] = fmaf(s[qt][kt][r] + pv[qt][kt][r], c1, pd_[qt][kt][r] * c2);

    // 3. prefetch next tile's K / pos / pad (consumed next iteration)
    load_k(kn);
    load_pp(kn);

    // 4. online softmax (per q-row = per (qt,r) across the 16 lanes of a row)
    #pragma unroll
    for (int qt = 0; qt < 2; ++qt)
    #pragma unroll
    for (int r = 0; r < 4; ++r){
      float s0 = sc[qt][0][r], s1 = sc[qt][1][r];
      float mx = rmax16(fmaxf(s0, s1));
      float mo = m_[qt][r];
      float mn = fmaxf(mo, mx);
      float alpha = exp2f(mo - mn);
      m_[qt][r] = mn;
      float p0 = exp2f(s0 - mn);
      float p1 = exp2f(s1 - mn);
      float ps = rsum16(p0 + p1);
      l_[qt][r] = l_[qt][r] * alpha + ps;
      O[qt][0][r] *= alpha;
      O[qt][1][r] *= alpha;
      // pack (kt0,kt1) -> dword c: bf16 slot 2c holds k=c, slot 2c+1 holds k=c+16
      u32 pk = (u32)f2bf(p0) | ((u32)f2bf(p1) << 16);
      p_lds[w][qt*16 + g*4 + r][c] = pk;
    }

    // 5. PV: read P as A-fragments (scalar u32 reads, same type as writes), V as B
    #pragma unroll
    for (int qt = 0; qt < 2; ++qt){
      int row = qt*16 + c;
      u32 t0 = p_lds[w][row][g*4 + 0];
      u32 t1 = p_lds[w][row][g*4 + 1];
      u32 t2 = p_lds[w][row][g*4 + 2];
      u32 t3 = p_lds[w][row][g*4 + 3];
      u32x4 tv = { t0, t1, t2, t3 };
      bf16x8 pa = __builtin_bit_cast(bf16x8, tv);
      O[qt][0] = MFMA(pa, vf[0], O[qt][0]);
      O[qt][1] = MFMA(pa, vf[1], O[qt][1]);
    }
    // 6. prefetch next V
    load_v(kn);
  }

  // epilogue: normalize and store ctx (B*T, 256) bf16
  #pragma unroll
  for (int qt = 0; qt < 2; ++qt)
  #pragma unroll
  for (int r = 0; r < 4; ++r){
    float inv = 1.0f / l_[qt][r];
    int q = q0 + qt*16 + g*4 + r;
    size_t base = (size_t)(b*2048 + q) * 256 + w*32;
    ctx[base +      c] = f2bf(O[qt][0][r] * inv);
    ctx[base + 16 + c] = f2bf(O[qt][1][r] * inv);
  }
}

// ---------------- kernel 3a/3c: GEMM (A @ W^T + bias + resid) + LayerNorm -----
// grid (256): m-block of 32. block 512: wave w covers cols 32w..32w+31 (N=256).
__global__ __launch_bounds__(512) void gemm_ln_kernel(
    const u16* __restrict__ A, const u16* __restrict__ Wt,
    const float* __restrict__ bias, const float* __restrict__ resid,
    const float* __restrict__ gam, const float* __restrict__ bet,
    float* __restrict__ outF, u16* __restrict__ outB,
    int lda, int ksteps)
{
  __shared__ float sm1[32][8], sm2[32][8];
  const int tid = threadIdx.x;
  const int lane = tid & 63, w = tid >> 6;
  const int g = lane >> 4, c = lane & 15;
  const int m0 = blockIdx.x * 32;
  const int n0 = w * 32;

  const u16* Am = A  + (size_t)m0 * lda;
  const u16* Wn = Wt + (size_t)n0 * lda;

  f32x4 acc[2][2];
  #pragma unroll
  for (int i = 0; i < 2; ++i)
    #pragma unroll
    for (int j = 0; j < 2; ++j){ f32x4 z = {0.f,0.f,0.f,0.f}; acc[i][j] = z; }

  #pragma unroll 2
  for (int kt = 0; kt < ksteps; ++kt){
    bf16x8 a0 = ld_bf8(Am + (size_t)(     c) * lda + kt*32 + g*8);
    bf16x8 a1 = ld_bf8(Am + (size_t)(16 + c) * lda + kt*32 + g*8);
    bf16x8 b0 = ld_bf8(Wn + (size_t)(     c) * lda + kt*32 + g*8);
    bf16x8 b1 = ld_bf8(Wn + (size_t)(16 + c) * lda + kt*32 + g*8);
    acc[0][0] = MFMA(a0, b0, acc[0][0]);
    acc[0][1] = MFMA(a0, b1, acc[0][1]);
    acc[1][0] = MFMA(a1, b0, acc[1][0]);
    acc[1][1] = MFMA(a1, b1, acc[1][1]);
  }

  float val[2][2][4];
  #pragma unroll
  for (int qt = 0; qt < 2; ++qt)
  #pragma unroll
  for (int nt = 0; nt < 2; ++nt)
  #pragma unroll
  for (int r = 0; r < 4; ++r){
    int mrow = m0 + qt*16 + g*4 + r;
    int col  = n0 + nt*16 + c;
    val[qt][nt][r] = acc[qt][nt][r] + bias[col] + resid[(size_t)mrow*256 + col];
  }

  // per-row partial sums (this wave's 32 cols), all lanes of a row agree
  #pragma unroll
  for (int qt = 0; qt < 2; ++qt)
  #pragma unroll
  for (int r = 0; r < 4; ++r){
    float v0 = val[qt][0][r], v1 = val[qt][1][r];
    float p1 = rsum16(v0 + v1);
    float p2 = rsum16(v0*v0 + v1*v1);
    if (c == 0){
      int rr = qt*16 + g*4 + r;
      sm1[rr][w] = p1; sm2[rr][w] = p2;
    }
  }
  __syncthreads();

  #pragma unroll
  for (int qt = 0; qt < 2; ++qt)
  #pragma unroll
  for (int r = 0; r < 4; ++r){
    int rr = qt*16 + g*4 + r;
    float S1 = 0.f, S2 = 0.f;
    #pragma unroll
    for (int j = 0; j < 8; ++j){ S1 += sm1[rr][j]; S2 += sm2[rr][j]; }
    float mean = S1 * (1.0f/256.0f);
    float var  = S2 * (1.0f/256.0f) - mean*mean;
    float rstd = rsqrtf(var + 1e-5f);
    int mrow = m0 + rr;
    #pragma unroll
    for (int nt = 0; nt < 2; ++nt){
      int col = n0 + nt*16 + c;
      float y = (val[qt][nt][r] - mean) * rstd * gam[col] + bet[col];
      outF[(size_t)mrow*256 + col] = y;
      if (outB) outB[(size_t)mrow*256 + col] = f2bf(y);
    }
  }
}

// ---------------- kernel 3b: FFN first GEMM + LeakyReLU -----------------------
// grid (256, 4): m-block, n-chunk of 256. block 512.
__global__ __launch_bounds__(512) void ffn1_kernel(
    const u16* __restrict__ X1, const u16* __restrict__ W1b,
    const float* __restrict__ b1, u16* __restrict__ Hb)
{
  const int tid = threadIdx.x;
  const int lane = tid & 63, w = tid >> 6;
  const int g = lane >> 4, c = lane & 15;
  const int m0 = blockIdx.x * 32;
  const int n0 = blockIdx.y * 256 + w * 32;

  const u16* Am = X1  + (size_t)m0 * 256;
  const u16* Wn = W1b + (size_t)n0 * 256;

  f32x4 acc[2][2];
  #pragma unroll
  for (int i = 0; i < 2; ++i)
    #pragma unroll
    for (int j = 0; j < 2; ++j){ f32x4 z = {0.f,0.f,0.f,0.f}; acc[i][j] = z; }

  #pragma unroll
  for (int kt = 0; kt < 8; ++kt){
    bf16x8 a0 = ld_bf8(Am + (size_t)(     c) * 256 + kt*32 + g*8);
    bf16x8 a1 = ld_bf8(Am + (size_t)(16 + c) * 256 + kt*32 + g*8);
    bf16x8 b0 = ld_bf8(Wn + (size_t)(     c) * 256 + kt*32 + g*8);
    bf16x8 b1 = ld_bf8(Wn + (size_t)(16 + c) * 256 + kt*32 + g*8);
    acc[0][0] = MFMA(a0, b0, acc[0][0]);
    acc[0][1] = MFMA(a0, b1, acc[0][1]);
    acc[1][0] = MFMA(a1, b0, acc[1][0]);
    acc[1][1] = MFMA(a1, b1, acc[1][1]);
  }

  #pragma unroll
  for (int qt = 0; qt < 2; ++qt)
  #pragma unroll
  for (int nt = 0; nt < 2; ++nt)
  #pragma unroll
  for (int r = 0; r < 4; ++r){
    int mrow = m0 + qt*16 + g*4 + r;
    int col  = n0 + nt*16 + c;
    float v = acc[qt][nt][r] + b1[col];
    v = (v >= 0.f) ? v : v * 0.01f;
    Hb[(size_t)mrow*1024 + col] = f2bf(v);
  }
}

// ---------------- launcher ----------------------------------------------------
extern "C" void kernel_launch(void* const* d_in, const int* in_sizes, int n_in,
                              void* d_out, int out_size, void* d_ws, size_t ws_size,
                              hipStream_t stream)
{
  (void)in_sizes; (void)n_in; (void)out_size; (void)ws_size;
  const float* x   = (const float*)d_in[0];
  const float* pos = (const float*)d_in[1];
  const float* pad = (const float*)d_in[2];
  const float* Wq  = (const float*)d_in[3];
  const float* bq  = (const float*)d_in[4];
  const float* Wk  = (const float*)d_in[5];
  const float* bk  = (const float*)d_in[6];
  const float* Wv  = (const float*)d_in[7];
  const float* bv  = (const float*)d_in[8];
  const float* Wo  = (const float*)d_in[9];
  const float* bo  = (const float*)d_in[10];
  const float* W1  = (const float*)d_in[11];
  const float* b1  = (const float*)d_in[12];
  const float* W2  = (const float*)d_in[13];
  const float* b2  = (const float*)d_in[14];
  const float* g1  = (const float*)d_in[15];
  const float* be1 = (const float*)d_in[16];
  const float* g2  = (const float*)d_in[17];
  const float* be2 = (const float*)d_in[18];

  char* ws = (char*)d_ws;
  u16* wsX  = (u16*)(ws + OFF_X);
  u16* wsW3 = (u16*)(ws + OFF_WQ);
  u16* wsWo = (u16*)(ws + OFF_WO);
  u16* wsW1 = (u16*)(ws + OFF_W1);
  u16* wsW2 = (u16*)(ws + OFF_W2);
  u16* Qb   = (u16*)(ws + OFF_Q);
  u16* Kb   = (u16*)(ws + OFF_K);
  u16* VTb  = (u16*)(ws + OFF_VT);
  u16* ctx  = (u16*)(ws + OFF_CTX);
  float* x1f = (float*)(ws + OFF_X1F);
  u16* x1b  = (u16*)(ws + OFF_X1B);
  u16* hb   = (u16*)(ws + OFF_H);

  prep_kernel<<<11264, 256, 0, stream>>>(x, Wq, Wk, Wv, Wo, W1, W2, wsX);
  qkv_kernel<<<dim3(256, 3), 512, 0, stream>>>(wsX, wsW3, bq, bk, bv, Qb, Kb, VTb);
  attn_kernel<<<dim3(64, 4), 512, 0, stream>>>(pos, pad, Qb, Kb, VTb, ctx);
  gemm_ln_kernel<<<256, 512, 0, stream>>>(ctx, wsWo, bo, x, g1, be1, x1f, x1b, 256, 8);
  ffn1_kernel<<<dim3(256, 4), 512, 0, stream>>>(x1b, wsW1, b1, hb);
  gemm_ln_kernel<<<256, 512, 0, stream>>>(hb, wsW2, b2, x1f, g2, be2,
                                          (float*)d_out, (u16*)nullptr, 1024, 32);
}

// Round 2
// 302.647 us; speedup vs baseline: 1.6243x; 1.6243x over previous
//
#include <hip/hip_runtime.h>

typedef unsigned short u16;
typedef unsigned int   u32;
typedef float f32x4 __attribute__((ext_vector_type(4)));
typedef u32   u32x4 __attribute__((ext_vector_type(4)));
typedef __bf16 bf16x8 __attribute__((ext_vector_type(8)));

// ---------------- workspace byte offsets (total 0x3180000 = 51.9 MB) ----------
#define OFF_X    0x0000000ULL  // x bf16            (8192*256)   4 MB
#define OFF_WQ   0x0400000ULL  // Wq bf16           (256*256)
#define OFF_WK   0x0420000ULL
#define OFF_WV   0x0440000ULL
#define OFF_WO   0x0460000ULL
#define OFF_W1   0x0480000ULL  // (1024*256)
#define OFF_W2   0x0500000ULL  // (256*1024)
#define OFF_Q    0x0580000ULL  // Q  bf16 (B,H,T,D) 4 MB
#define OFF_K    0x0980000ULL  // K  bf16 (B,H,T,D) 4 MB
#define OFF_VT   0x0D80000ULL  // V^T bf16 (B,H,D,T) row-permuted within 32-tiles, 4 MB
#define OFF_CTX  0x1180000ULL  // ctx bf16 (8192,256) 4 MB
#define OFF_X1F  0x1580000ULL  // x1 f32  (8192,256) 8 MB
#define OFF_X1B  0x1D80000ULL  // x1 bf16            4 MB
#define OFF_H    0x2180000ULL  // h bf16 (8192,1024) 16 MB

__device__ __forceinline__ u16 f2bf(float f){
  u32 u = __float_as_uint(f);
  return (u16)((u + 0x7FFFu + ((u >> 16) & 1u)) >> 16);
}
__device__ __forceinline__ bf16x8 ld_bf8(const u16* p){
  return *(const bf16x8*)p;   // 16B global load; p always 16B aligned
}
__device__ __forceinline__ f32x4 ntld4(const float* p){
  return __builtin_nontemporal_load((const f32x4*)p);
}
__device__ __forceinline__ float ntld(const float* p){
  return __builtin_nontemporal_load(p);
}
__device__ __forceinline__ f32x4 MFMA(bf16x8 a, bf16x8 b, f32x4 c){
  return __builtin_amdgcn_mfma_f32_16x16x32_bf16(a, b, c, 0, 0, 0);
}
template<int C>
__device__ __forceinline__ float dpp_rot(float x){
  int i = __float_as_int(x);
  return __int_as_float(__builtin_amdgcn_update_dpp(i, i, C, 0xF, 0xF, false));
}
// all-reduce across the 16 lanes of a DPP row (ror 1,2,4,8)
__device__ __forceinline__ float rmax16(float x){
  x = fmaxf(x, dpp_rot<0x121>(x)); x = fmaxf(x, dpp_rot<0x122>(x));
  x = fmaxf(x, dpp_rot<0x124>(x)); x = fmaxf(x, dpp_rot<0x128>(x));
  return x;
}
__device__ __forceinline__ float rsum16(float x){
  x += dpp_rot<0x121>(x); x += dpp_rot<0x122>(x);
  x += dpp_rot<0x124>(x); x += dpp_rot<0x128>(x);
  return x;
}

// ---------------- kernel 0: convert x + all weights to bf16 -------------------
__global__ __launch_bounds__(256) void prep_kernel(
    const float* __restrict__ x,  const float* __restrict__ Wq,
    const float* __restrict__ Wk, const float* __restrict__ Wv,
    const float* __restrict__ Wo, const float* __restrict__ W1,
    const float* __restrict__ W2, u16* __restrict__ dst)
{
  int i = blockIdx.x * 256 + threadIdx.x;   // grid sized exactly to 2883584
  float v;
  if (i < 2097152) v = x[i];
  else {
    int j = i - 2097152;
    if      (j <  65536) v = Wq[j];
    else if (j < 131072) v = Wk[j -  65536];
    else if (j < 196608) v = Wv[j - 131072];
    else if (j < 262144) v = Wo[j - 196608];
    else if (j < 524288) v = W1[j - 262144];
    else                 v = W2[j - 524288];
  }
  dst[i] = f2bf(v);
}

// ---------------- kernel 1: QKV projection ------------------------------------
__global__ __launch_bounds__(512) void qkv_kernel(
    const u16* __restrict__ X, const u16* __restrict__ W3,
    const float* __restrict__ bq, const float* __restrict__ bk,
    const float* __restrict__ bv,
    u16* __restrict__ Q, u16* __restrict__ K, u16* __restrict__ VT)
{
  const int tid = threadIdx.x;
  const int lane = tid & 63, w = tid >> 6;
  const int g = lane >> 4, c = lane & 15;
  const int m0 = blockIdx.x * 32;
  const int nb = blockIdx.y;
  const u16* Wb = W3 + nb * 65536;
  const float* bias = (nb == 0) ? bq : ((nb == 1) ? bk : bv);
  const int n0 = w * 32;

  f32x4 acc[2][2];
  #pragma unroll
  for (int i = 0; i < 2; ++i)
    #pragma unroll
    for (int j = 0; j < 2; ++j){ f32x4 z = {0.f,0.f,0.f,0.f}; acc[i][j] = z; }

  #pragma unroll
  for (int kt = 0; kt < 8; ++kt){
    bf16x8 a0 = ld_bf8(X  + (size_t)(m0 +      c) * 256 + kt*32 + g*8);
    bf16x8 a1 = ld_bf8(X  + (size_t)(m0 + 16 + c) * 256 + kt*32 + g*8);
    bf16x8 b0 = ld_bf8(Wb + (size_t)(n0 +      c) * 256 + kt*32 + g*8);
    bf16x8 b1 = ld_bf8(Wb + (size_t)(n0 + 16 + c) * 256 + kt*32 + g*8);
    acc[0][0] = MFMA(a0, b0, acc[0][0]);
    acc[0][1] = MFMA(a0, b1, acc[0][1]);
    acc[1][0] = MFMA(a1, b0, acc[1][0]);
    acc[1][1] = MFMA(a1, b1, acc[1][1]);
  }

  #pragma unroll
  for (int qt = 0; qt < 2; ++qt)
  #pragma unroll
  for (int nt = 0; nt < 2; ++nt)
  #pragma unroll
  for (int r = 0; r < 4; ++r){
    int mrow = m0 + qt*16 + g*4 + r;
    int col  = n0 + nt*16 + c;
    float v = acc[qt][nt][r] + bias[col];
    int bi = mrow >> 11, t = mrow & 2047;
    int h  = col >> 5,  d = col & 31;
    u16 hv = f2bf(v);
    if (nb == 0)      Q[((size_t)(bi*8 + h) * 2048 + t) * 32 + d] = hv;
    else if (nb == 1) K[((size_t)(bi*8 + h) * 2048 + t) * 32 + d] = hv;
    else {
      // store V transposed (B,H,D,T) with t permuted inside each 32-tile so that
      // stored slot s holds actual t-offset 16*(s&1) + (s>>1)  (matches P packing)
      int tl = t & 31;
      int sl = ((tl & 15) << 1) | (tl >> 4);
      VT[((size_t)(bi*8 + h) * 32 + d) * 2048 + (t & ~31) + sl] = hv;
    }
  }
}

// ---------------- kernel 2: fused flash attention with pos bias ---------------
// 256 WGs, 1D grid, XCD-swizzled: xcd = bid&7, b = xcd>>1, qtile = (bid>>3)*2|(xcd&1).
// block 512: wave = head. K-tile = 64 per iteration (two 32-sub-chunks).
// Fused bias (pos*c1 + pad*c2) cooperatively staged into double-buffered LDS,
// layout [h][qr][k ^ swz(qr)], swz(qr) = ((qr>>2&1)<<4)|((qr>>3&1)<<2)  (2-way max).
__global__ __launch_bounds__(512) void attn_kernel(
    const float* __restrict__ pos, const float* __restrict__ pad,
    const u16* __restrict__ Q, const u16* __restrict__ K,
    const u16* __restrict__ VT, u16* __restrict__ ctx)
{
  __shared__ float bias_lds[2][16384];   // 2 x 64 KB: [buf][h*2048 + qr*64 + kswz]
  __shared__ u32 p_lds[8][32][20];       // per-wave P tile

  const int tid = threadIdx.x;
  const int lane = tid & 63, w = tid >> 6;
  const int g = lane >> 4, c = lane & 15;
  const int bid = blockIdx.x;
  const int xcd = bid & 7;
  const int b = xcd >> 1;
  const int qtile = ((bid >> 3) << 1) | (xcd & 1);
  const int q0 = qtile * 32;
  const int swzL = ((g & 1) << 4) | ((g & 2) << 1);   // read-side swz (qr bits 2,3 = g)
  const int swzS = ((w & 1) << 4) | ((w & 2) << 1);   // store-side swz (qr = w*4+j)

  const u16* Qb  = Q  + ((size_t)(b*8 + w) * 2048 + q0) * 32;
  const u16* Kb  = K  +  (size_t)(b*8 + w) * 2048 * 32;
  const u16* VTb = VT +  (size_t)(b*8 + w) * 32 * 2048;

  const float c1 = 1.4426950408889634f * 0.17677669529663689f; // log2e / sqrt(32)
  const float c2 = 1.4426950408889634f;                        // log2e

  bf16x8 qf[2];
  qf[0] = ld_bf8(Qb + (size_t)(     c) * 32 + g*8);
  qf[1] = ld_bf8(Qb + (size_t)(16 + c) * 32 + g*8);

  f32x4 O[2][2];
  #pragma unroll
  for (int i = 0; i < 2; ++i)
    #pragma unroll
    for (int j = 0; j < 2; ++j){ f32x4 z = {0.f,0.f,0.f,0.f}; O[i][j] = z; }
  float m_[2][4], l_[2][4];
  #pragma unroll
  for (int i = 0; i < 2; ++i)
    #pragma unroll
    for (int r = 0; r < 4; ++r){ m_[i][r] = -3.0e38f; l_[i][r] = 0.f; }

  // staging registers (tile being prefetched)
  f32x4 sv[8];   // [j*2+m] pos float4: row qr=w*4+j, k = m*32 + (lane>>1), h = (lane&1)*4..+3
  float sp[8];   // matching pad scalars
  bf16x8 kf[4], vf[4], knf[4], vnf[4];

  const int kl  = lane >> 1;          // k within 32-chunk covered by this lane's float4
  const int h0  = (lane & 1) * 4;     // first h of this lane's float4

  auto stage_load = [&](int k0){
    #pragma unroll
    for (int j = 0; j < 4; ++j){
      int qr = w*4 + j;
      const float* pr = pos + ((size_t)((b*2048 + q0 + qr)) * 2048 + k0) * 8;
      sv[j*2+0] = ntld4(pr + lane*4);
      sv[j*2+1] = ntld4(pr + lane*4 + 256);
      const float* dr = pad + (size_t)(b*2048 + q0 + qr) * 2048 + k0 + kl;
      sp[j*2+0] = ntld(dr);
      sp[j*2+1] = ntld(dr + 32);
    }
  };
  auto stage_write = [&](float* bl){
    #pragma unroll
    for (int j = 0; j < 4; ++j){
      int qr = w*4 + j;
      #pragma unroll
      for (int m = 0; m < 2; ++m){
        float pdv = sp[j*2+m] * c2;
        int idx = qr*64 + ((m*32 + kl) ^ swzS);
        #pragma unroll
        for (int j2 = 0; j2 < 4; ++j2)
          bl[(h0 + j2)*2048 + idx] = fmaf(sv[j*2+m][j2], c1, pdv);
      }
    }
  };
  auto load_kv = [&](int k0, bf16x8* kd, bf16x8* vd){
    kd[0] = ld_bf8(Kb + (size_t)(k0 +      c) * 32 + g*8);
    kd[1] = ld_bf8(Kb + (size_t)(k0 + 16 + c) * 32 + g*8);
    kd[2] = ld_bf8(Kb + (size_t)(k0 + 32 + c) * 32 + g*8);
    kd[3] = ld_bf8(Kb + (size_t)(k0 + 48 + c) * 32 + g*8);
    vd[0] = ld_bf8(VTb + (size_t)(     c) * 2048 + k0      + g*8);
    vd[1] = ld_bf8(VTb + (size_t)(16 + c) * 2048 + k0      + g*8);
    vd[2] = ld_bf8(VTb + (size_t)(     c) * 2048 + k0 + 32 + g*8);
    vd[3] = ld_bf8(VTb + (size_t)(16 + c) * 2048 + k0 + 32 + g*8);
  };

  // prologue: stage tile 0
  stage_load(0);
  load_kv(0, kf, vf);
  stage_write(&bias_lds[0][0]);
  __syncthreads();

  auto body = [&](int kn, const float* blc, float* bln){
    // issue next tile's loads early (overlap with compute)
    stage_load(kn);
    load_kv(kn, knf, vnf);

    // compute current tile: two 32-k sub-chunks
    #pragma unroll
    for (int s = 0; s < 2; ++s){
      f32x4 sS[2][2];
      {
        f32x4 z = {0.f,0.f,0.f,0.f};
        sS[0][0] = MFMA(qf[0], kf[2*s+0], z);
        sS[0][1] = MFMA(qf[0], kf[2*s+1], z);
        sS[1][0] = MFMA(qf[1], kf[2*s+0], z);
        sS[1][1] = MFMA(qf[1], kf[2*s+1], z);
      }
      float sc[2][2][4];
      #pragma unroll
      for (int qt = 0; qt < 2; ++qt)
      #pragma unroll
      for (int kt = 0; kt < 2; ++kt)
      #pragma unroll
      for (int r = 0; r < 4; ++r){
        float bv_ = blc[w*2048 + (qt*16 + g*4 + r)*64 + ((s*32 + kt*16 + c) ^ swzL)];
        sc[qt][kt][r] = fmaf(sS[qt][kt][r], c1, bv_);
      }
      #pragma unroll
      for (int qt = 0; qt < 2; ++qt)
      #pragma unroll
      for (int r = 0; r < 4; ++r){
        float s0 = sc[qt][0][r], s1 = sc[qt][1][r];
        float mx = rmax16(fmaxf(s0, s1));
        float mo = m_[qt][r];
        float mn = fmaxf(mo, mx);
        float alpha = exp2f(mo - mn);
        m_[qt][r] = mn;
        float p0 = exp2f(s0 - mn);
        float p1 = exp2f(s1 - mn);
        float ps = rsum16(p0 + p1);
        l_[qt][r] = l_[qt][r] * alpha + ps;
        O[qt][0][r] *= alpha;
        O[qt][1][r] *= alpha;
        u32 pk = (u32)f2bf(p0) | ((u32)f2bf(p1) << 16);
        p_lds[w][qt*16 + g*4 + r][c] = pk;
      }
      #pragma unroll
      for (int qt = 0; qt < 2; ++qt){
        int row = qt*16 + c;
        u32 t0 = p_lds[w][row][g*4 + 0];
        u32 t1 = p_lds[w][row][g*4 + 1];
        u32 t2 = p_lds[w][row][g*4 + 2];
        u32 t3 = p_lds[w][row][g*4 + 3];
        u32x4 tv = { t0, t1, t2, t3 };
        bf16x8 pa = __builtin_bit_cast(bf16x8, tv);
        O[qt][0] = MFMA(pa, vf[2*s+0], O[qt][0]);
        O[qt][1] = MFMA(pa, vf[2*s+1], O[qt][1]);
      }
    }

    // write next tile's bias, rotate K/V regs, barrier
    stage_write(bln);
    #pragma unroll
    for (int i = 0; i < 4; ++i){ kf[i] = knf[i]; vf[i] = vnf[i]; }
    __syncthreads();
  };

  for (int itp = 0; itp < 16; ++itp){
    int it0 = itp*2;
    int kc0 = it0 * 64;
    body(kc0 + 64,                          &bias_lds[0][0], &bias_lds[1][0]);
    body((it0 + 1 < 31) ? kc0 + 128 : 0,    &bias_lds[1][0], &bias_lds[0][0]);
  }

  // epilogue: normalize and store ctx (B*T, 256) bf16
  #pragma unroll
  for (int qt = 0; qt < 2; ++qt)
  #pragma unroll
  for (int r = 0; r < 4; ++r){
    float inv = 1.0f / l_[qt][r];
    int q = q0 + qt*16 + g*4 + r;
    size_t base = (size_t)(b*2048 + q) * 256 + w*32;
    ctx[base +      c] = f2bf(O[qt][0][r] * inv);
    ctx[base + 16 + c] = f2bf(O[qt][1][r] * inv);
  }
}

// ---------------- kernel 3a/3c: GEMM (A @ W^T + bias + resid) + LayerNorm -----
__global__ __launch_bounds__(512) void gemm_ln_kernel(
    const u16* __restrict__ A, const u16* __restrict__ Wt,
    const float* __restrict__ bias, const float* __restrict__ resid,
    const float* __restrict__ gam, const float* __restrict__ bet,
    float* __restrict__ outF, u16* __restrict__ outB,
    int lda, int ksteps)
{
  __shared__ float sm1[32][8], sm2[32][8];
  const int tid = threadIdx.x;
  const int lane = tid & 63, w = tid >> 6;
  const int g = lane >> 4, c = lane & 15;
  const int m0 = blockIdx.x * 32;
  const int n0 = w * 32;

  const u16* Am = A  + (size_t)m0 * lda;
  const u16* Wn = Wt + (size_t)n0 * lda;

  f32x4 acc[2][2];
  #pragma unroll
  for (int i = 0; i < 2; ++i)
    #pragma unroll
    for (int j = 0; j < 2; ++j){ f32x4 z = {0.f,0.f,0.f,0.f}; acc[i][j] = z; }

  #pragma unroll 2
  for (int kt = 0; kt < ksteps; ++kt){
    bf16x8 a0 = ld_bf8(Am + (size_t)(     c) * lda + kt*32 + g*8);
    bf16x8 a1 = ld_bf8(Am + (size_t)(16 + c) * lda + kt*32 + g*8);
    bf16x8 b0 = ld_bf8(Wn + (size_t)(     c) * lda + kt*32 + g*8);
    bf16x8 b1 = ld_bf8(Wn + (size_t)(16 + c) * lda + kt*32 + g*8);
    acc[0][0] = MFMA(a0, b0, acc[0][0]);
    acc[0][1] = MFMA(a0, b1, acc[0][1]);
    acc[1][0] = MFMA(a1, b0, acc[1][0]);
    acc[1][1] = MFMA(a1, b1, acc[1][1]);
  }

  float val[2][2][4];
  #pragma unroll
  for (int qt = 0; qt < 2; ++qt)
  #pragma unroll
  for (int nt = 0; nt < 2; ++nt)
  #pragma unroll
  for (int r = 0; r < 4; ++r){
    int mrow = m0 + qt*16 + g*4 + r;
    int col  = n0 + nt*16 + c;
    val[qt][nt][r] = acc[qt][nt][r] + bias[col] + resid[(size_t)mrow*256 + col];
  }

  #pragma unroll
  for (int qt = 0; qt < 2; ++qt)
  #pragma unroll
  for (int r = 0; r < 4; ++r){
    float v0 = val[qt][0][r], v1 = val[qt][1][r];
    float p1 = rsum16(v0 + v1);
    float p2 = rsum16(v0*v0 + v1*v1);
    if (c == 0){
      int rr = qt*16 + g*4 + r;
      sm1[rr][w] = p1; sm2[rr][w] = p2;
    }
  }
  __syncthreads();

  #pragma unroll
  for (int qt = 0; qt < 2; ++qt)
  #pragma unroll
  for (int r = 0; r < 4; ++r){
    int rr = qt*16 + g*4 + r;
    float S1 = 0.f, S2 = 0.f;
    #pragma unroll
    for (int j = 0; j < 8; ++j){ S1 += sm1[rr][j]; S2 += sm2[rr][j]; }
    float mean = S1 * (1.0f/256.0f);
    float var  = S2 * (1.0f/256.0f) - mean*mean;
    float rstd = rsqrtf(var + 1e-5f);
    int mrow = m0 + rr;
    #pragma unroll
    for (int nt = 0; nt < 2; ++nt){
      int col = n0 + nt*16 + c;
      float y = (val[qt][nt][r] - mean) * rstd * gam[col] + bet[col];
      outF[(size_t)mrow*256 + col] = y;
      if (outB) outB[(size_t)mrow*256 + col] = f2bf(y);
    }
  }
}

// ---------------- kernel 3b: FFN first GEMM + LeakyReLU -----------------------
__global__ __launch_bounds__(512) void ffn1_kernel(
    const u16* __restrict__ X1, const u16* __restrict__ W1b,
    const float* __restrict__ b1, u16* __restrict__ Hb)
{
  const int tid = threadIdx.x;
  const int lane = tid & 63, w = tid >> 6;
  const int g = lane >> 4, c = lane & 15;
  const int m0 = blockIdx.x * 32;
  const int n0 = blockIdx.y * 256 + w * 32;

  const u16* Am = X1  + (size_t)m0 * 256;
  const u16* Wn = W1b + (size_t)n0 * 256;

  f32x4 acc[2][2];
  #pragma unroll
  for (int i = 0; i < 2; ++i)
    #pragma unroll
    for (int j = 0; j < 2; ++j){ f32x4 z = {0.f,0.f,0.f,0.f}; acc[i][j] = z; }

  #pragma unroll
  for (int kt = 0; kt < 8; ++kt){
    bf16x8 a0 = ld_bf8(Am + (size_t)(     c) * 256 + kt*32 + g*8);
    bf16x8 a1 = ld_bf8(Am + (size_t)(16 + c) * 256 + kt*32 + g*8);
    bf16x8 b0 = ld_bf8(Wn + (size_t)(     c) * 256 + kt*32 + g*8);
    bf16x8 b1 = ld_bf8(Wn + (size_t)(16 + c) * 256 + kt*32 + g*8);
    acc[0][0] = MFMA(a0, b0, acc[0][0]);
    acc[0][1] = MFMA(a0, b1, acc[0][1]);
    acc[1][0] = MFMA(a1, b0, acc[1][0]);
    acc[1][1] = MFMA(a1, b1, acc[1][1]);
  }

  #pragma unroll
  for (int qt = 0; qt < 2; ++qt)
  #pragma unroll
  for (int nt = 0; nt < 2; ++nt)
  #pragma unroll
  for (int r = 0; r < 4; ++r){
    int mrow = m0 + qt*16 + g*4 + r;
    int col  = n0 + nt*16 + c;
    float v = acc[qt][nt][r] + b1[col];
    v = (v >= 0.f) ? v : v * 0.01f;
    Hb[(size_t)mrow*1024 + col] = f2bf(v);
  }
}

// ---------------- launcher ----------------------------------------------------
extern "C" void kernel_launch(void* const* d_in, const int* in_sizes, int n_in,
                              void* d_out, int out_size, void* d_ws, size_t ws_size,
                              hipStream_t stream)
{
  (void)in_sizes; (void)n_in; (void)out_size; (void)ws_size;
  const float* x   = (const float*)d_in[0];
  const float* pos = (const float*)d_in[1];
  const float* pad = (const float*)d_in[2];
  const float* Wq  = (const float*)d_in[3];
  const float* bq  = (const float*)d_in[4];
  const float* Wk  = (const float*)d_in[5];
  const float* bk  = (const float*)d_in[6];
  const float* Wv  = (const float*)d_in[7];
  const float* bv  = (const float*)d_in[8];
  const float* Wo  = (const float*)d_in[9];
  const float* bo  = (const float*)d_in[10];
  const float* W1  = (const float*)d_in[11];
  const float* b1  = (const float*)d_in[12];
  const float* W2  = (const float*)d_in[13];
  const float* b2  = (const float*)d_in[14];
  const float* g1  = (const float*)d_in[15];
  const float* be1 = (const float*)d_in[16];
  const float* g2  = (const float*)d_in[17];
  const float* be2 = (const float*)d_in[18];

  char* ws = (char*)d_ws;
  u16* wsX  = (u16*)(ws + OFF_X);
  u16* wsW3 = (u16*)(ws + OFF_WQ);
  u16* wsWo = (u16*)(ws + OFF_WO);
  u16* wsW1 = (u16*)(ws + OFF_W1);
  u16* wsW2 = (u16*)(ws + OFF_W2);
  u16* Qb   = (u16*)(ws + OFF_Q);
  u16* Kb   = (u16*)(ws + OFF_K);
  u16* VTb  = (u16*)(ws + OFF_VT);
  u16* ctx  = (u16*)(ws + OFF_CTX);
  float* x1f = (float*)(ws + OFF_X1F);
  u16* x1b  = (u16*)(ws + OFF_X1B);
  u16* hb   = (u16*)(ws + OFF_H);

  prep_kernel<<<11264, 256, 0, stream>>>(x, Wq, Wk, Wv, Wo, W1, W2, wsX);
  qkv_kernel<<<dim3(256, 3), 512, 0, stream>>>(wsX, wsW3, bq, bk, bv, Qb, Kb, VTb);
  attn_kernel<<<256, 512, 0, stream>>>(pos, pad, Qb, Kb, VTb, ctx);
  gemm_ln_kernel<<<256, 512, 0, stream>>>(ctx, wsWo, bo, x, g1, be1, x1f, x1b, 256, 8);
  ffn1_kernel<<<dim3(256, 4), 512, 0, stream>>>(x1b, wsW1, b1, hb);
  gemm_ln_kernel<<<256, 512, 0, stream>>>(hb, wsW2, b2, x1f, g2, be2,
                                          (float*)d_out, (u16*)nullptr, 1024, 32);
}